// Round 9
// baseline (491.685 us; speedup 1.0000x reference)
//
#include <hip/hip_runtime.h>
#include <cmath>

#define NN    4096
#define FIN   32
#define KSEL  39      // neighbors kept (top-40 minus self)
#define PP    22
#define PPAD  24
#define FOUT  48
#define WPB   2       // waves per block
#define QW    4       // queries per wave
#define CAP   128     // candidate cap per query (fallback if exceeded)

#define WSYNC() asm volatile("s_waitcnt lgkmcnt(0)" ::: "memory")

// ---------------- precompute: one thread per point -------------------------------
__global__ __launch_bounds__(256) void gn_pre(
    const float* __restrict__ x,
    const float* __restrict__ Wf, const float* __restrict__ bf,
    const float* __restrict__ Ws, const float* __restrict__ bs,
    float* __restrict__ coords4, float* __restrict__ feats)
{
    int p = blockIdx.x * 256 + threadIdx.x;

    const float4* xr4 = (const float4*)(x + (size_t)p * FIN);
    float xv[FIN];
    #pragma unroll
    for (int i = 0; i < 8; ++i) {
        float4 t = xr4[i];
        xv[4*i] = t.x; xv[4*i+1] = t.y; xv[4*i+2] = t.z; xv[4*i+3] = t.w;
    }

    float fa[PP];
    #pragma unroll
    for (int c = 0; c < PP; ++c) fa[c] = bf[c];
    #pragma unroll
    for (int i = 0; i < FIN; ++i) {
        float xi = xv[i];
        #pragma unroll
        for (int c = 0; c < PP; ++c) fa[c] = fmaf(xi, Wf[i * PP + c], fa[c]);
    }

    float ca[4];
    #pragma unroll
    for (int c = 0; c < 4; ++c) ca[c] = bs[c];
    #pragma unroll
    for (int i = 0; i < FIN; ++i) {
        float xi = xv[i];
        #pragma unroll
        for (int c = 0; c < 4; ++c) ca[c] = fmaf(xi, Ws[i * 4 + c], ca[c]);
    }

    float4* fw = (float4*)(feats + (size_t)p * PPAD);
    fw[0] = make_float4(fa[0],  fa[1],  fa[2],  fa[3]);
    fw[1] = make_float4(fa[4],  fa[5],  fa[6],  fa[7]);
    fw[2] = make_float4(fa[8],  fa[9],  fa[10], fa[11]);
    fw[3] = make_float4(fa[12], fa[13], fa[14], fa[15]);
    fw[4] = make_float4(fa[16], fa[17], fa[18], fa[19]);
    fw[5] = make_float4(fa[20], fa[21], 0.f, 0.f);

    ((float4*)coords4)[p] = make_float4(ca[0], ca[1], ca[2], ca[3]);
}

// ---- fallback-only helpers (degenerate C > CAP path) ----------------------------
__device__ __forceinline__ void sort64_pair(float& v, int& m, int lane) {
    #pragma unroll
    for (int k = 2; k <= 64; k <<= 1) {
        #pragma unroll
        for (int j = k >> 1; j >= 1; j >>= 1) {
            float ov = __shfl_xor(v, j);
            int   om = __shfl_xor(m, j);
            bool keepMin = (((lane & j) == 0) == ((lane & k) == 0));
            bool less = (ov < v) || (ov == v && om < m);
            bool take = (less == keepMin);
            v = take ? ov : v;
            m = take ? om : m;
        }
    }
}
__device__ __forceinline__ void merge64(float& Lv, int& Lm, float cv, int cm, int lane) {
    float rv = __shfl_xor(cv, 63);
    int   rm = __shfl_xor(cm, 63);
    bool less = (rv < Lv) || (rv == Lv && rm < Lm);
    if (less) { Lv = rv; Lm = rm; }
    #pragma unroll
    for (int j = 32; j >= 1; j >>= 1) {
        float ov = __shfl_xor(Lv, j);
        int   om = __shfl_xor(Lm, j);
        bool lower = ((lane & j) == 0);
        bool l2 = (ov < Lv) || (ov == Lv && om < Lm);
        bool take = (l2 == lower);
        Lv = take ? ov : Lv;
        Lm = take ? om : Lm;
    }
}

// ---------------- main: one wave per FOUR queries --------------------------------
__global__ __launch_bounds__(WPB * 64, 5) void gn_main(
    const float* __restrict__ x,
    const float* __restrict__ Wo, const float* __restrict__ bo,
    const float* __restrict__ coords4, const float* __restrict__ feats,
    float* __restrict__ out)
{
    __shared__ unsigned short sel_s[WPB * QW * CAP];     // candidate indices
    __shared__ float fstage_s[WPB * KSEL * PPAD];
    __shared__ float agg_s[WPB * 48];
    __shared__ unsigned cnt_s[WPB * QW];
    __shared__ unsigned cnt2_s[WPB];

    const float INF = __builtin_inff();
    const float NEGINF = -INF;
    const int wv    = threadIdx.x >> 6;
    const int lane  = threadIdx.x & 63;
    const int qbase = (blockIdx.x * WPB + wv) * QW;      // 4 queries, same batch
    const int b     = qbase >> 12;
    const int n0    = qbase & (NN - 1);
    unsigned short* selp = sel_s + wv * QW * CAP;
    float* fstage = fstage_s + wv * (KSEL * PPAD);
    float* agg    = agg_s + wv * 48;

    const float4* c4 = ((const float4*)coords4) + (size_t)b * NN;

    // per-query constants
    float sqn[QW], m2x[QW], m2y[QW], m2z[QW], m2w[QW];
    #pragma unroll
    for (int j = 0; j < QW; ++j) {
        float4 cq = c4[n0 + j];
        sqn[j] = fmaf(cq.x, cq.x, fmaf(cq.y, cq.y, fmaf(cq.z, cq.z, cq.w * cq.w)));
        m2x[j] = -2.f * cq.x; m2y[j] = -2.f * cq.y;
        m2z[j] = -2.f * cq.z; m2w[j] = -2.f * cq.w;
    }

    if (lane < QW) cnt_s[wv * QW + lane] = 0;

    // ---- pass 1: shared coordinate loads, per-query running min (self incl) ----
    float km[QW];
    #pragma unroll
    for (int j = 0; j < QW; ++j) km[j] = INF;
    #pragma unroll 2
    for (int i = 0; i < 64; ++i) {
        float4 cm = c4[i * 64 + lane];
        #pragma unroll
        for (int j = 0; j < QW; ++j) {
            float d = fmaf(cm.x, cm.x + m2x[j], sqn[j]);
            d = fmaf(cm.y, cm.y + m2y[j], d);
            d = fmaf(cm.z, cm.z + m2z[j], d);
            d = fmaf(cm.w, cm.w + m2w[j], d);
            km[j] = fminf(km[j], d);
        }
    }
    unsigned kb[QW];
    #pragma unroll
    for (int j = 0; j < QW; ++j) kb[j] = __float_as_uint(fmaxf(km[j], 0.f));

    // ---- bounds: exact 40th-smallest lane-min per query, 4 interleaved radixes ----
    unsigned ub[QW] = {0, 0, 0, 0};
    for (int bit = 30; bit >= 0; --bit) {
        #pragma unroll
        for (int j = 0; j < QW; ++j) {
            unsigned t = ub[j] | (1u << bit);
            int c = (int)__popcll(__ballot(kb[j] < t));
            if (c < KSEL + 1) ub[j] = t;
        }
    }
    float UBf[QW];
    #pragma unroll
    for (int j = 0; j < QW; ++j) UBf[j] = __uint_as_float(ub[j]);
    WSYNC();   // cnt init visible

    // ---- compact pass: shared loads, per-query candidate index lists ----
    #pragma unroll 2
    for (int i = 0; i < 64; ++i) {
        int m = i * 64 + lane;
        float4 cm = c4[m];
        #pragma unroll
        for (int j = 0; j < QW; ++j) {
            float d = fmaf(cm.x, cm.x + m2x[j], sqn[j]);
            d = fmaf(cm.y, cm.y + m2y[j], d);
            d = fmaf(cm.z, cm.z + m2z[j], d);
            d = fmaf(cm.w, cm.w + m2w[j], d);
            if ((d <= UBf[j]) && (m != n0 + j)) {
                unsigned s = atomicAdd(&cnt_s[wv * QW + j], 1u);
                if (s < CAP) selp[j * CAP + s] = (unsigned short)m;
            }
        }
    }
    WSYNC();

    // ---- per query: exact top-39 selection + stage + aggregate + epilogue ----
    #pragma unroll 1
    for (int j = 0; j < QW; ++j) {
        int nj = n0 + j;
        int C = (int)cnt_s[wv * QW + j];
        if (lane == 0) cnt2_s[wv] = 0;
        WSYNC();

        if (C <= CAP) {
            // load candidates (<=2 chunks), recompute exact clamped d2
            unsigned kd[2]; unsigned ki[2]; float dv[2];
            #pragma unroll
            for (int ch = 0; ch < 2; ++ch) {
                int s = ch * 64 + lane;
                unsigned idx = 0xFFFFFFFFu, kk = 0xFFFFFFFFu;
                float dd = 0.f;
                if (s < C) {
                    idx = (unsigned)selp[j * CAP + s];
                    float4 cm = c4[idx];
                    float d = fmaf(cm.x, cm.x + m2x[j], sqn[j]);
                    d = fmaf(cm.y, cm.y + m2y[j], d);
                    d = fmaf(cm.z, cm.z + m2z[j], d);
                    d = fmaf(cm.w, cm.w + m2w[j], d);
                    d = fmaxf(d, 0.f);
                    dd = d; kk = __float_as_uint(d);
                }
                kd[ch] = kk; ki[ch] = idx; dv[ch] = dd;
            }
            // D = exact 39th-smallest clamped d2 bits
            unsigned D = 0;
            for (int bit = 30; bit >= 0; --bit) {
                unsigned t = D | (1u << bit);
                int c = (int)__popcll(__ballot(kd[0] < t))
                      + (int)__popcll(__ballot(kd[1] < t));
                if (c < KSEL) D = t;
            }
            int cless  = (int)__popcll(__ballot(kd[0] < D))
                       + (int)__popcll(__ballot(kd[1] < D));
            int tiecnt = (int)__popcll(__ballot(kd[0] == D))
                       + (int)__popcll(__ballot(kd[1] == D));
            int tneed = KSEL - cless;
            unsigned TI = 0xFFFFFFFFu;
            if (tiecnt > tneed) {            // rare: resolve ties by lowest index
                unsigned pi = 0;
                for (int bit = 11; bit >= 0; --bit) {
                    unsigned t = pi | (1u << bit);
                    int c = (int)__popcll(__ballot((kd[0] == D) && (ki[0] < t)))
                          + (int)__popcll(__ballot((kd[1] == D) && (ki[1] < t)));
                    if (c < tneed) pi = t;
                }
                TI = pi;
            }
            // stage the exactly-39 selected neighbors
            #pragma unroll
            for (int ch = 0; ch < 2; ++ch) {
                bool take = (kd[ch] < D) || ((kd[ch] == D) && (ki[ch] <= TI));
                if (take) {
                    unsigned slot = atomicAdd(&cnt2_s[wv], 1u);
                    float wgt = __expf(-10.f * dv[ch]);
                    const float4* fr = (const float4*)(feats + ((size_t)b * NN + ki[ch]) * PPAD);
                    float4 f0 = fr[0], f1 = fr[1], f2 = fr[2], f3 = fr[3], f4 = fr[4], f5 = fr[5];
                    float4* row = (float4*)(fstage + slot * PPAD);
                    row[0] = make_float4(f0.x * wgt, f0.y * wgt, f0.z * wgt, f0.w * wgt);
                    row[1] = make_float4(f1.x * wgt, f1.y * wgt, f1.z * wgt, f1.w * wgt);
                    row[2] = make_float4(f2.x * wgt, f2.y * wgt, f2.z * wgt, f2.w * wgt);
                    row[3] = make_float4(f3.x * wgt, f3.y * wgt, f3.z * wgt, f3.w * wgt);
                    row[4] = make_float4(f4.x * wgt, f4.y * wgt, f4.z * wgt, f4.w * wgt);
                    row[5] = make_float4(f5.x * wgt, f5.y * wgt, f5.z * wgt, f5.w * wgt);
                }
            }
        } else {
            // degenerate fallback: exact streaming top-64 over all 4096
            float Lv = INF; int Lm = 0x7FFFFFFF;
            for (int c = 0; c < 64; ++c) {
                int m = c * 64 + lane;
                float4 cm = c4[m];
                float v = fmaf(cm.x, cm.x + m2x[j], sqn[j]);
                v = fmaf(cm.y, cm.y + m2y[j], v);
                v = fmaf(cm.z, cm.z + m2z[j], v);
                v = fmaf(cm.w, cm.w + m2w[j], v);
                v = fmaxf(v, 0.f);
                if (m == nj) v = INF;
                sort64_pair(v, m, lane);
                if (c == 0) { Lv = v; Lm = m; }
                else        merge64(Lv, Lm, v, m, lane);
            }
            if (lane < KSEL) {
                float wgt = __expf(-10.f * Lv);
                const float4* fr = (const float4*)(feats + ((size_t)b * NN + Lm) * PPAD);
                float4 f0 = fr[0], f1 = fr[1], f2 = fr[2], f3 = fr[3], f4 = fr[4], f5 = fr[5];
                float4* row = (float4*)(fstage + lane * PPAD);
                row[0] = make_float4(f0.x * wgt, f0.y * wgt, f0.z * wgt, f0.w * wgt);
                row[1] = make_float4(f1.x * wgt, f1.y * wgt, f1.z * wgt, f1.w * wgt);
                row[2] = make_float4(f2.x * wgt, f2.y * wgt, f2.z * wgt, f2.w * wgt);
                row[3] = make_float4(f3.x * wgt, f3.y * wgt, f3.z * wgt, f3.w * wgt);
                row[4] = make_float4(f4.x * wgt, f4.y * wgt, f4.z * wgt, f4.w * wgt);
                row[5] = make_float4(f5.x * wgt, f5.y * wgt, f5.z * wgt, f5.w * wgt);
            }
        }
        WSYNC();

        // ---- max / mean over 39 neighbors: 44 lanes, split-k ----
        if (lane < 2 * PP) {
            int g  = (lane >= PP) ? 1 : 0;
            int c  = lane - g * PP;
            int k0 = g ? 20 : 0;
            int k1 = g ? KSEL : 20;
            float mx = NEGINF, sm = 0.f;
            for (int k = k0; k < k1; ++k) {
                float v = fstage[k * PPAD + c];
                mx = fmaxf(mx, v);
                sm += v;
            }
            float mx2 = __shfl(mx, lane + PP);
            float sm2 = __shfl(sm, lane + PP);
            if (lane < PP) {
                agg[c]      = fmaxf(mx, mx2);
                agg[PP + c] = (sm + sm2) * (1.f / (float)KSEL);
            }
        }
        WSYNC();

        // ---- epilogue: out = tanh([x | max | mean] @ Wo + bo), fast tanh ----
        if (lane < FOUT) {
            const float* xr = x + (size_t)(qbase + j) * FIN;
            float acc = bo[lane];
            #pragma unroll
            for (int f = 0; f < FIN; ++f)
                acc = fmaf(xr[f], Wo[f * FOUT + lane], acc);
            #pragma unroll
            for (int f = 0; f < 2 * PP; ++f)
                acc = fmaf(agg[f], Wo[(FIN + f) * FOUT + lane], acc);
            float e = __expf(2.f * acc);
            float r = __builtin_amdgcn_rcpf(e + 1.f);
            out[(size_t)(qbase + j) * FOUT + lane] = fmaf(-2.f, r, 1.f);
        }
        WSYNC();
    }
}

extern "C" void kernel_launch(void* const* d_in, const int* in_sizes, int n_in,
                              void* d_out, int out_size, void* d_ws, size_t ws_size,
                              hipStream_t stream) {
    const float* x  = (const float*)d_in[0];
    const float* Wf = (const float*)d_in[1];
    const float* bf = (const float*)d_in[2];
    const float* Ws = (const float*)d_in[3];
    const float* bs = (const float*)d_in[4];
    const float* Wo = (const float*)d_in[5];
    const float* bo = (const float*)d_in[6];
    float* outp = (float*)d_out;

    float* ws      = (float*)d_ws;
    float* coords4 = ws;                      // 32768*4  = 131072 floats
    float* feats   = ws + 131072;             // 32768*24 = 786432 floats

    gn_pre<<<32768 / 256, 256, 0, stream>>>(x, Wf, bf, Ws, bs, coords4, feats);
    gn_main<<<32768 / (WPB * QW), WPB * 64, 0, stream>>>(x, Wo, bo, coords4, feats, outp);
}

// Round 10
// 463.657 us; speedup vs baseline: 1.0604x; 1.0604x over previous
//
#include <hip/hip_runtime.h>
#include <cmath>

#define NN    4096
#define FIN   32
#define KSEL  39      // neighbors kept (top-40 minus self)
#define PP    22
#define PPAD  24
#define FOUT  48
#define WPB   2       // waves per block
#define QW    4       // queries per wave
#define CAP   128     // candidate cap per query (fallback if exceeded)

#define WSYNC() asm volatile("s_waitcnt lgkmcnt(0)" ::: "memory")

// ---------------- precompute: one thread per point -------------------------------
__global__ __launch_bounds__(256) void gn_pre(
    const float* __restrict__ x,
    const float* __restrict__ Wf, const float* __restrict__ bf,
    const float* __restrict__ Ws, const float* __restrict__ bs,
    float* __restrict__ coords4, float* __restrict__ feats)
{
    int p = blockIdx.x * 256 + threadIdx.x;

    const float4* xr4 = (const float4*)(x + (size_t)p * FIN);
    float xv[FIN];
    #pragma unroll
    for (int i = 0; i < 8; ++i) {
        float4 t = xr4[i];
        xv[4*i] = t.x; xv[4*i+1] = t.y; xv[4*i+2] = t.z; xv[4*i+3] = t.w;
    }

    float fa[PP];
    #pragma unroll
    for (int c = 0; c < PP; ++c) fa[c] = bf[c];
    #pragma unroll
    for (int i = 0; i < FIN; ++i) {
        float xi = xv[i];
        #pragma unroll
        for (int c = 0; c < PP; ++c) fa[c] = fmaf(xi, Wf[i * PP + c], fa[c]);
    }

    float ca[4];
    #pragma unroll
    for (int c = 0; c < 4; ++c) ca[c] = bs[c];
    #pragma unroll
    for (int i = 0; i < FIN; ++i) {
        float xi = xv[i];
        #pragma unroll
        for (int c = 0; c < 4; ++c) ca[c] = fmaf(xi, Ws[i * 4 + c], ca[c]);
    }

    float4* fw = (float4*)(feats + (size_t)p * PPAD);
    fw[0] = make_float4(fa[0],  fa[1],  fa[2],  fa[3]);
    fw[1] = make_float4(fa[4],  fa[5],  fa[6],  fa[7]);
    fw[2] = make_float4(fa[8],  fa[9],  fa[10], fa[11]);
    fw[3] = make_float4(fa[12], fa[13], fa[14], fa[15]);
    fw[4] = make_float4(fa[16], fa[17], fa[18], fa[19]);
    fw[5] = make_float4(fa[20], fa[21], 0.f, 0.f);

    ((float4*)coords4)[p] = make_float4(ca[0], ca[1], ca[2], ca[3]);
}

// ---- fallback-only helpers (degenerate C > CAP path) ----------------------------
__device__ __forceinline__ void sort64_pair(float& v, int& m, int lane) {
    #pragma unroll
    for (int k = 2; k <= 64; k <<= 1) {
        #pragma unroll
        for (int j = k >> 1; j >= 1; j >>= 1) {
            float ov = __shfl_xor(v, j);
            int   om = __shfl_xor(m, j);
            bool keepMin = (((lane & j) == 0) == ((lane & k) == 0));
            bool less = (ov < v) || (ov == v && om < m);
            bool take = (less == keepMin);
            v = take ? ov : v;
            m = take ? om : m;
        }
    }
}
__device__ __forceinline__ void merge64(float& Lv, int& Lm, float cv, int cm, int lane) {
    float rv = __shfl_xor(cv, 63);
    int   rm = __shfl_xor(cm, 63);
    bool less = (rv < Lv) || (rv == Lv && rm < Lm);
    if (less) { Lv = rv; Lm = rm; }
    #pragma unroll
    for (int j = 32; j >= 1; j >>= 1) {
        float ov = __shfl_xor(Lv, j);
        int   om = __shfl_xor(Lm, j);
        bool lower = ((lane & j) == 0);
        bool l2 = (ov < Lv) || (ov == Lv && om < Lm);
        bool take = (l2 == lower);
        Lv = take ? ov : Lv;
        Lm = take ? om : Lm;
    }
}

// ---------------- main: one wave per FOUR queries --------------------------------
__global__ __launch_bounds__(WPB * 64, 5) void gn_main(
    const float* __restrict__ x,
    const float* __restrict__ Wo, const float* __restrict__ bo,
    const float* __restrict__ coords4, const float* __restrict__ feats,
    float* __restrict__ out)
{
    __shared__ unsigned short sel_s[WPB * QW * CAP];     // candidate indices
    __shared__ float fstage_s[WPB * KSEL * PPAD];
    __shared__ float agg_s[WPB * 48];
    __shared__ unsigned cnt_s[WPB * QW];
    __shared__ unsigned cnt2_s[WPB];

    const float INF = __builtin_inff();
    const float NEGINF = -INF;
    const int wv    = threadIdx.x >> 6;
    const int lane  = threadIdx.x & 63;
    const int qbase = (blockIdx.x * WPB + wv) * QW;      // 4 queries, same batch
    const int b     = qbase >> 12;
    const int n0    = qbase & (NN - 1);
    unsigned short* selp = sel_s + wv * QW * CAP;
    float* fstage = fstage_s + wv * (KSEL * PPAD);
    float* agg    = agg_s + wv * 48;

    const float4* c4 = ((const float4*)coords4) + (size_t)b * NN;

    // per-query constants (ONLY used inside fully-unrolled loops -> registers)
    float sqn[QW], m2x[QW], m2y[QW], m2z[QW], m2w[QW];
    #pragma unroll
    for (int j = 0; j < QW; ++j) {
        float4 cq = c4[n0 + j];
        sqn[j] = fmaf(cq.x, cq.x, fmaf(cq.y, cq.y, fmaf(cq.z, cq.z, cq.w * cq.w)));
        m2x[j] = -2.f * cq.x; m2y[j] = -2.f * cq.y;
        m2z[j] = -2.f * cq.z; m2w[j] = -2.f * cq.w;
    }

    if (lane < QW) cnt_s[wv * QW + lane] = 0;

    // ---- pass 1: shared coordinate loads, per-query running min (self incl) ----
    float km[QW];
    #pragma unroll
    for (int j = 0; j < QW; ++j) km[j] = INF;
    #pragma unroll 2
    for (int i = 0; i < 64; ++i) {
        float4 cm = c4[i * 64 + lane];
        #pragma unroll
        for (int j = 0; j < QW; ++j) {
            float d = fmaf(cm.x, cm.x + m2x[j], sqn[j]);
            d = fmaf(cm.y, cm.y + m2y[j], d);
            d = fmaf(cm.z, cm.z + m2z[j], d);
            d = fmaf(cm.w, cm.w + m2w[j], d);
            km[j] = fminf(km[j], d);
        }
    }
    unsigned kb[QW];
    #pragma unroll
    for (int j = 0; j < QW; ++j) kb[j] = __float_as_uint(fmaxf(km[j], 0.f));

    // ---- bounds: exact 40th-smallest lane-min per query, 4 interleaved radixes ----
    unsigned ub[QW] = {0, 0, 0, 0};
    for (int bit = 30; bit >= 0; --bit) {
        #pragma unroll
        for (int j = 0; j < QW; ++j) {
            unsigned t = ub[j] | (1u << bit);
            int c = (int)__popcll(__ballot(kb[j] < t));
            if (c < KSEL + 1) ub[j] = t;
        }
    }
    float UBf[QW];
    #pragma unroll
    for (int j = 0; j < QW; ++j) UBf[j] = __uint_as_float(ub[j]);
    WSYNC();   // cnt init visible

    // ---- compact pass: shared loads, per-query candidate index lists ----
    #pragma unroll 2
    for (int i = 0; i < 64; ++i) {
        int m = i * 64 + lane;
        float4 cm = c4[m];
        #pragma unroll
        for (int j = 0; j < QW; ++j) {
            float d = fmaf(cm.x, cm.x + m2x[j], sqn[j]);
            d = fmaf(cm.y, cm.y + m2y[j], d);
            d = fmaf(cm.z, cm.z + m2z[j], d);
            d = fmaf(cm.w, cm.w + m2w[j], d);
            if ((d <= UBf[j]) && (m != n0 + j)) {
                unsigned s = atomicAdd(&cnt_s[wv * QW + j], 1u);
                if (s < CAP) selp[j * CAP + s] = (unsigned short)m;
            }
        }
    }
    WSYNC();

    // ---- per query: exact top-39 selection + stage + aggregate + epilogue ----
    // NOTE: runtime loop over j -> NO thread-private array may be indexed by j here
    // (that demotes the array to scratch: R9's 30x HBM-traffic regression).
    // Per-query constants are rebuilt as scalars from a uniform L1-hot load.
    #pragma unroll 1
    for (int j = 0; j < QW; ++j) {
        int nj = n0 + j;
        float4 cqj = c4[nj];
        float sqnj = fmaf(cqj.x, cqj.x, fmaf(cqj.y, cqj.y, fmaf(cqj.z, cqj.z, cqj.w * cqj.w)));
        float m2xj = -2.f * cqj.x, m2yj = -2.f * cqj.y;
        float m2zj = -2.f * cqj.z, m2wj = -2.f * cqj.w;

        int C = (int)cnt_s[wv * QW + j];
        if (lane == 0) cnt2_s[wv] = 0;
        WSYNC();

        if (C <= CAP) {
            // load candidates (<=2 chunks), recompute exact clamped d2
            unsigned kd0, kd1, ki0, ki1; float dv0, dv1;
            {
                int s = lane;
                unsigned idx = 0xFFFFFFFFu, kk = 0xFFFFFFFFu; float dd = 0.f;
                if (s < C) {
                    idx = (unsigned)selp[j * CAP + s];
                    float4 cm = c4[idx];
                    float d = fmaf(cm.x, cm.x + m2xj, sqnj);
                    d = fmaf(cm.y, cm.y + m2yj, d);
                    d = fmaf(cm.z, cm.z + m2zj, d);
                    d = fmaf(cm.w, cm.w + m2wj, d);
                    d = fmaxf(d, 0.f);
                    dd = d; kk = __float_as_uint(d);
                }
                kd0 = kk; ki0 = idx; dv0 = dd;
            }
            {
                int s = 64 + lane;
                unsigned idx = 0xFFFFFFFFu, kk = 0xFFFFFFFFu; float dd = 0.f;
                if (s < C) {
                    idx = (unsigned)selp[j * CAP + s];
                    float4 cm = c4[idx];
                    float d = fmaf(cm.x, cm.x + m2xj, sqnj);
                    d = fmaf(cm.y, cm.y + m2yj, d);
                    d = fmaf(cm.z, cm.z + m2zj, d);
                    d = fmaf(cm.w, cm.w + m2wj, d);
                    d = fmaxf(d, 0.f);
                    dd = d; kk = __float_as_uint(d);
                }
                kd1 = kk; ki1 = idx; dv1 = dd;
            }
            // D = exact 39th-smallest clamped d2 bits
            unsigned D = 0;
            for (int bit = 30; bit >= 0; --bit) {
                unsigned t = D | (1u << bit);
                int c = (int)__popcll(__ballot(kd0 < t))
                      + (int)__popcll(__ballot(kd1 < t));
                if (c < KSEL) D = t;
            }
            int cless  = (int)__popcll(__ballot(kd0 < D))
                       + (int)__popcll(__ballot(kd1 < D));
            int tiecnt = (int)__popcll(__ballot(kd0 == D))
                       + (int)__popcll(__ballot(kd1 == D));
            int tneed = KSEL - cless;
            unsigned TI = 0xFFFFFFFFu;
            if (tiecnt > tneed) {            // rare: resolve ties by lowest index
                unsigned pi = 0;
                for (int bit = 11; bit >= 0; --bit) {
                    unsigned t = pi | (1u << bit);
                    int c = (int)__popcll(__ballot((kd0 == D) && (ki0 < t)))
                          + (int)__popcll(__ballot((kd1 == D) && (ki1 < t)));
                    if (c < tneed) pi = t;
                }
                TI = pi;
            }
            // stage the exactly-39 selected neighbors
            {
                bool take = (kd0 < D) || ((kd0 == D) && (ki0 <= TI));
                if (take) {
                    unsigned slot = atomicAdd(&cnt2_s[wv], 1u);
                    float wgt = __expf(-10.f * dv0);
                    const float4* fr = (const float4*)(feats + ((size_t)b * NN + ki0) * PPAD);
                    float4 f0 = fr[0], f1 = fr[1], f2 = fr[2], f3 = fr[3], f4 = fr[4], f5 = fr[5];
                    float4* row = (float4*)(fstage + slot * PPAD);
                    row[0] = make_float4(f0.x * wgt, f0.y * wgt, f0.z * wgt, f0.w * wgt);
                    row[1] = make_float4(f1.x * wgt, f1.y * wgt, f1.z * wgt, f1.w * wgt);
                    row[2] = make_float4(f2.x * wgt, f2.y * wgt, f2.z * wgt, f2.w * wgt);
                    row[3] = make_float4(f3.x * wgt, f3.y * wgt, f3.z * wgt, f3.w * wgt);
                    row[4] = make_float4(f4.x * wgt, f4.y * wgt, f4.z * wgt, f4.w * wgt);
                    row[5] = make_float4(f5.x * wgt, f5.y * wgt, f5.z * wgt, f5.w * wgt);
                }
            }
            {
                bool take = (kd1 < D) || ((kd1 == D) && (ki1 <= TI));
                if (take) {
                    unsigned slot = atomicAdd(&cnt2_s[wv], 1u);
                    float wgt = __expf(-10.f * dv1);
                    const float4* fr = (const float4*)(feats + ((size_t)b * NN + ki1) * PPAD);
                    float4 f0 = fr[0], f1 = fr[1], f2 = fr[2], f3 = fr[3], f4 = fr[4], f5 = fr[5];
                    float4* row = (float4*)(fstage + slot * PPAD);
                    row[0] = make_float4(f0.x * wgt, f0.y * wgt, f0.z * wgt, f0.w * wgt);
                    row[1] = make_float4(f1.x * wgt, f1.y * wgt, f1.z * wgt, f1.w * wgt);
                    row[2] = make_float4(f2.x * wgt, f2.y * wgt, f2.z * wgt, f2.w * wgt);
                    row[3] = make_float4(f3.x * wgt, f3.y * wgt, f3.z * wgt, f3.w * wgt);
                    row[4] = make_float4(f4.x * wgt, f4.y * wgt, f4.z * wgt, f4.w * wgt);
                    row[5] = make_float4(f5.x * wgt, f5.y * wgt, f5.z * wgt, f5.w * wgt);
                }
            }
        } else {
            // degenerate fallback: exact streaming top-64 over all 4096
            float Lv = INF; int Lm = 0x7FFFFFFF;
            for (int c = 0; c < 64; ++c) {
                int m = c * 64 + lane;
                float4 cm = c4[m];
                float v = fmaf(cm.x, cm.x + m2xj, sqnj);
                v = fmaf(cm.y, cm.y + m2yj, v);
                v = fmaf(cm.z, cm.z + m2zj, v);
                v = fmaf(cm.w, cm.w + m2wj, v);
                v = fmaxf(v, 0.f);
                if (m == nj) v = INF;
                sort64_pair(v, m, lane);
                if (c == 0) { Lv = v; Lm = m; }
                else        merge64(Lv, Lm, v, m, lane);
            }
            if (lane < KSEL) {
                float wgt = __expf(-10.f * Lv);
                const float4* fr = (const float4*)(feats + ((size_t)b * NN + Lm) * PPAD);
                float4 f0 = fr[0], f1 = fr[1], f2 = fr[2], f3 = fr[3], f4 = fr[4], f5 = fr[5];
                float4* row = (float4*)(fstage + lane * PPAD);
                row[0] = make_float4(f0.x * wgt, f0.y * wgt, f0.z * wgt, f0.w * wgt);
                row[1] = make_float4(f1.x * wgt, f1.y * wgt, f1.z * wgt, f1.w * wgt);
                row[2] = make_float4(f2.x * wgt, f2.y * wgt, f2.z * wgt, f2.w * wgt);
                row[3] = make_float4(f3.x * wgt, f3.y * wgt, f3.z * wgt, f3.w * wgt);
                row[4] = make_float4(f4.x * wgt, f4.y * wgt, f4.z * wgt, f4.w * wgt);
                row[5] = make_float4(f5.x * wgt, f5.y * wgt, f5.z * wgt, f5.w * wgt);
            }
        }
        WSYNC();

        // ---- max / mean over 39 neighbors: 44 lanes, split-k ----
        if (lane < 2 * PP) {
            int g  = (lane >= PP) ? 1 : 0;
            int c  = lane - g * PP;
            int k0 = g ? 20 : 0;
            int k1 = g ? KSEL : 20;
            float mx = NEGINF, sm = 0.f;
            for (int k = k0; k < k1; ++k) {
                float v = fstage[k * PPAD + c];
                mx = fmaxf(mx, v);
                sm += v;
            }
            float mx2 = __shfl(mx, lane + PP);
            float sm2 = __shfl(sm, lane + PP);
            if (lane < PP) {
                agg[c]      = fmaxf(mx, mx2);
                agg[PP + c] = (sm + sm2) * (1.f / (float)KSEL);
            }
        }
        WSYNC();

        // ---- epilogue: out = tanh([x | max | mean] @ Wo + bo), fast tanh ----
        if (lane < FOUT) {
            const float* xr = x + (size_t)(qbase + j) * FIN;
            float acc = bo[lane];
            #pragma unroll
            for (int f = 0; f < FIN; ++f)
                acc = fmaf(xr[f], Wo[f * FOUT + lane], acc);
            #pragma unroll
            for (int f = 0; f < 2 * PP; ++f)
                acc = fmaf(agg[f], Wo[(FIN + f) * FOUT + lane], acc);
            float e = __expf(2.f * acc);
            float r = __builtin_amdgcn_rcpf(e + 1.f);
            out[(size_t)(qbase + j) * FOUT + lane] = fmaf(-2.f, r, 1.f);
        }
        WSYNC();
    }
}

extern "C" void kernel_launch(void* const* d_in, const int* in_sizes, int n_in,
                              void* d_out, int out_size, void* d_ws, size_t ws_size,
                              hipStream_t stream) {
    const float* x  = (const float*)d_in[0];
    const float* Wf = (const float*)d_in[1];
    const float* bf = (const float*)d_in[2];
    const float* Ws = (const float*)d_in[3];
    const float* bs = (const float*)d_in[4];
    const float* Wo = (const float*)d_in[5];
    const float* bo = (const float*)d_in[6];
    float* outp = (float*)d_out;

    float* ws      = (float*)d_ws;
    float* coords4 = ws;                      // 32768*4  = 131072 floats
    float* feats   = ws + 131072;             // 32768*24 = 786432 floats

    gn_pre<<<32768 / 256, 256, 0, stream>>>(x, Wf, bf, Ws, bs, coords4, feats);
    gn_main<<<32768 / (WPB * QW), WPB * 64, 0, stream>>>(x, Wo, bo, coords4, feats, outp);
}

// Round 11
// 231.878 us; speedup vs baseline: 2.1204x; 1.9996x over previous
//
#include <hip/hip_runtime.h>
#include <cmath>

#define NN    4096
#define FIN   32
#define KSEL  39      // neighbors kept (top-40 minus self)
#define PP    22
#define PPAD  24
#define FOUT  48
#define WPB   2       // waves per block
#define QW    4       // queries per wave
#define CAP   128     // candidate cap per query (fallback if exceeded)

#define WSYNC() asm volatile("s_waitcnt lgkmcnt(0)" ::: "memory")

// ---------------- precompute: one thread per point -------------------------------
__global__ __launch_bounds__(256) void gn_pre(
    const float* __restrict__ x,
    const float* __restrict__ Wf, const float* __restrict__ bf,
    const float* __restrict__ Ws, const float* __restrict__ bs,
    float* __restrict__ coords4, float* __restrict__ feats)
{
    int p = blockIdx.x * 256 + threadIdx.x;

    const float4* xr4 = (const float4*)(x + (size_t)p * FIN);
    float xv[FIN];
    #pragma unroll
    for (int i = 0; i < 8; ++i) {
        float4 t = xr4[i];
        xv[4*i] = t.x; xv[4*i+1] = t.y; xv[4*i+2] = t.z; xv[4*i+3] = t.w;
    }

    float fa[PP];
    #pragma unroll
    for (int c = 0; c < PP; ++c) fa[c] = bf[c];
    #pragma unroll
    for (int i = 0; i < FIN; ++i) {
        float xi = xv[i];
        #pragma unroll
        for (int c = 0; c < PP; ++c) fa[c] = fmaf(xi, Wf[i * PP + c], fa[c]);
    }

    float ca[4];
    #pragma unroll
    for (int c = 0; c < 4; ++c) ca[c] = bs[c];
    #pragma unroll
    for (int i = 0; i < FIN; ++i) {
        float xi = xv[i];
        #pragma unroll
        for (int c = 0; c < 4; ++c) ca[c] = fmaf(xi, Ws[i * 4 + c], ca[c]);
    }

    float4* fw = (float4*)(feats + (size_t)p * PPAD);
    fw[0] = make_float4(fa[0],  fa[1],  fa[2],  fa[3]);
    fw[1] = make_float4(fa[4],  fa[5],  fa[6],  fa[7]);
    fw[2] = make_float4(fa[8],  fa[9],  fa[10], fa[11]);
    fw[3] = make_float4(fa[12], fa[13], fa[14], fa[15]);
    fw[4] = make_float4(fa[16], fa[17], fa[18], fa[19]);
    fw[5] = make_float4(fa[20], fa[21], 0.f, 0.f);

    ((float4*)coords4)[p] = make_float4(ca[0], ca[1], ca[2], ca[3]);
}

// ---- fallback-only helpers (degenerate C > CAP path) ----------------------------
__device__ __forceinline__ void sort64_pair(float& v, int& m, int lane) {
    #pragma unroll
    for (int k = 2; k <= 64; k <<= 1) {
        #pragma unroll
        for (int j = k >> 1; j >= 1; j >>= 1) {
            float ov = __shfl_xor(v, j);
            int   om = __shfl_xor(m, j);
            bool keepMin = (((lane & j) == 0) == ((lane & k) == 0));
            bool less = (ov < v) || (ov == v && om < m);
            bool take = (less == keepMin);
            v = take ? ov : v;
            m = take ? om : m;
        }
    }
}
__device__ __forceinline__ void merge64(float& Lv, int& Lm, float cv, int cm, int lane) {
    float rv = __shfl_xor(cv, 63);
    int   rm = __shfl_xor(cm, 63);
    bool less = (rv < Lv) || (rv == Lv && rm < Lm);
    if (less) { Lv = rv; Lm = rm; }
    #pragma unroll
    for (int j = 32; j >= 1; j >>= 1) {
        float ov = __shfl_xor(Lv, j);
        int   om = __shfl_xor(Lm, j);
        bool lower = ((lane & j) == 0);
        bool l2 = (ov < Lv) || (ov == Lv && om < Lm);
        bool take = (l2 == lower);
        Lv = take ? ov : Lv;
        Lm = take ? om : Lm;
    }
}

// ---------------- per-query tail: selection + stage + aggregate + epilogue -------
// ALL state is scalar. Called 4 times explicitly (no runtime-j loop, no arrays).
__device__ __forceinline__ void tail_query(
    int lane, int b, int nj, int qj, int C,
    const unsigned short* __restrict__ selq,
    const float4* __restrict__ c4, const float* __restrict__ feats,
    const float* __restrict__ x, const float* __restrict__ Wo,
    const float* __restrict__ bo,
    float* __restrict__ fstage, float* __restrict__ agg,
    unsigned* __restrict__ cnt2, float* __restrict__ out)
{
    const float INF = __builtin_inff();
    const float NEGINF = -INF;
    float4 cqj = c4[nj];
    float sqnj = fmaf(cqj.x, cqj.x, fmaf(cqj.y, cqj.y, fmaf(cqj.z, cqj.z, cqj.w * cqj.w)));

    if (lane == 0) *cnt2 = 0;
    WSYNC();

    if (C <= CAP) {
        unsigned kd0 = 0xFFFFFFFFu, ki0 = 0xFFFFFFFFu; float dv0 = 0.f;
        if (lane < C) {
            unsigned idx = (unsigned)selq[lane];
            float4 cm = c4[idx];
            float s2 = fmaf(cm.x, cm.x, fmaf(cm.y, cm.y, fmaf(cm.z, cm.z, cm.w * cm.w)));
            float dt = fmaf(cqj.x, cm.x, fmaf(cqj.y, cm.y, fmaf(cqj.z, cm.z, cqj.w * cm.w)));
            float d  = fmaxf(fmaf(-2.f, dt, s2 + sqnj), 0.f);
            dv0 = d; kd0 = __float_as_uint(d); ki0 = idx;
        }
        unsigned kd1 = 0xFFFFFFFFu, ki1 = 0xFFFFFFFFu; float dv1 = 0.f;
        if (64 + lane < C) {
            unsigned idx = (unsigned)selq[64 + lane];
            float4 cm = c4[idx];
            float s2 = fmaf(cm.x, cm.x, fmaf(cm.y, cm.y, fmaf(cm.z, cm.z, cm.w * cm.w)));
            float dt = fmaf(cqj.x, cm.x, fmaf(cqj.y, cm.y, fmaf(cqj.z, cm.z, cqj.w * cm.w)));
            float d  = fmaxf(fmaf(-2.f, dt, s2 + sqnj), 0.f);
            dv1 = d; kd1 = __float_as_uint(d); ki1 = idx;
        }
        // D = exact 39th-smallest clamped d2 bits
        unsigned D = 0;
        for (int bit = 30; bit >= 0; --bit) {
            unsigned t = D | (1u << bit);
            int c = (int)__popcll(__ballot(kd0 < t))
                  + (int)__popcll(__ballot(kd1 < t));
            if (c < KSEL) D = t;
        }
        int cless  = (int)__popcll(__ballot(kd0 < D))
                   + (int)__popcll(__ballot(kd1 < D));
        int tiecnt = (int)__popcll(__ballot(kd0 == D))
                   + (int)__popcll(__ballot(kd1 == D));
        int tneed = KSEL - cless;
        unsigned TI = 0xFFFFFFFFu;
        if (tiecnt > tneed) {            // rare: resolve ties by lowest index
            unsigned pi = 0;
            for (int bit = 11; bit >= 0; --bit) {
                unsigned t = pi | (1u << bit);
                int c = (int)__popcll(__ballot((kd0 == D) && (ki0 < t)))
                      + (int)__popcll(__ballot((kd1 == D) && (ki1 < t)));
                if (c < tneed) pi = t;
            }
            TI = pi;
        }
        // stage the exactly-39 selected neighbors
        bool take0 = (kd0 < D) || ((kd0 == D) && (ki0 <= TI));
        if (take0) {
            unsigned slot = atomicAdd(cnt2, 1u);
            float wgt = __expf(-10.f * dv0);
            const float4* fr = (const float4*)(feats + ((size_t)b * NN + ki0) * PPAD);
            float4 f0 = fr[0], f1 = fr[1], f2 = fr[2], f3 = fr[3], f4 = fr[4], f5 = fr[5];
            float4* row = (float4*)(fstage + slot * PPAD);
            row[0] = make_float4(f0.x * wgt, f0.y * wgt, f0.z * wgt, f0.w * wgt);
            row[1] = make_float4(f1.x * wgt, f1.y * wgt, f1.z * wgt, f1.w * wgt);
            row[2] = make_float4(f2.x * wgt, f2.y * wgt, f2.z * wgt, f2.w * wgt);
            row[3] = make_float4(f3.x * wgt, f3.y * wgt, f3.z * wgt, f3.w * wgt);
            row[4] = make_float4(f4.x * wgt, f4.y * wgt, f4.z * wgt, f4.w * wgt);
            row[5] = make_float4(f5.x * wgt, f5.y * wgt, f5.z * wgt, f5.w * wgt);
        }
        bool take1 = (kd1 < D) || ((kd1 == D) && (ki1 <= TI));
        if (take1) {
            unsigned slot = atomicAdd(cnt2, 1u);
            float wgt = __expf(-10.f * dv1);
            const float4* fr = (const float4*)(feats + ((size_t)b * NN + ki1) * PPAD);
            float4 f0 = fr[0], f1 = fr[1], f2 = fr[2], f3 = fr[3], f4 = fr[4], f5 = fr[5];
            float4* row = (float4*)(fstage + slot * PPAD);
            row[0] = make_float4(f0.x * wgt, f0.y * wgt, f0.z * wgt, f0.w * wgt);
            row[1] = make_float4(f1.x * wgt, f1.y * wgt, f1.z * wgt, f1.w * wgt);
            row[2] = make_float4(f2.x * wgt, f2.y * wgt, f2.z * wgt, f2.w * wgt);
            row[3] = make_float4(f3.x * wgt, f3.y * wgt, f3.z * wgt, f3.w * wgt);
            row[4] = make_float4(f4.x * wgt, f4.y * wgt, f4.z * wgt, f4.w * wgt);
            row[5] = make_float4(f5.x * wgt, f5.y * wgt, f5.z * wgt, f5.w * wgt);
        }
    } else {
        // degenerate fallback: exact streaming top-64 over all 4096
        float Lv = INF; int Lm = 0x7FFFFFFF;
        for (int c = 0; c < 64; ++c) {
            int m = c * 64 + lane;
            float4 cm = c4[m];
            float s2 = fmaf(cm.x, cm.x, fmaf(cm.y, cm.y, fmaf(cm.z, cm.z, cm.w * cm.w)));
            float dt = fmaf(cqj.x, cm.x, fmaf(cqj.y, cm.y, fmaf(cqj.z, cm.z, cqj.w * cm.w)));
            float v  = fmaxf(fmaf(-2.f, dt, s2 + sqnj), 0.f);
            if (m == nj) v = INF;
            sort64_pair(v, m, lane);
            if (c == 0) { Lv = v; Lm = m; }
            else        merge64(Lv, Lm, v, m, lane);
        }
        if (lane < KSEL) {
            float wgt = __expf(-10.f * Lv);
            const float4* fr = (const float4*)(feats + ((size_t)b * NN + Lm) * PPAD);
            float4 f0 = fr[0], f1 = fr[1], f2 = fr[2], f3 = fr[3], f4 = fr[4], f5 = fr[5];
            float4* row = (float4*)(fstage + lane * PPAD);
            row[0] = make_float4(f0.x * wgt, f0.y * wgt, f0.z * wgt, f0.w * wgt);
            row[1] = make_float4(f1.x * wgt, f1.y * wgt, f1.z * wgt, f1.w * wgt);
            row[2] = make_float4(f2.x * wgt, f2.y * wgt, f2.z * wgt, f2.w * wgt);
            row[3] = make_float4(f3.x * wgt, f3.y * wgt, f3.z * wgt, f3.w * wgt);
            row[4] = make_float4(f4.x * wgt, f4.y * wgt, f4.z * wgt, f4.w * wgt);
            row[5] = make_float4(f5.x * wgt, f5.y * wgt, f5.z * wgt, f5.w * wgt);
        }
    }
    WSYNC();

    // ---- max / mean over 39 neighbors: 44 lanes, split-k ----
    if (lane < 2 * PP) {
        int g  = (lane >= PP) ? 1 : 0;
        int c  = lane - g * PP;
        int k0 = g ? 20 : 0;
        int k1 = g ? KSEL : 20;
        float mx = NEGINF, sm = 0.f;
        for (int k = k0; k < k1; ++k) {
            float v = fstage[k * PPAD + c];
            mx = fmaxf(mx, v);
            sm += v;
        }
        float mx2 = __shfl(mx, lane + PP);
        float sm2 = __shfl(sm, lane + PP);
        if (lane < PP) {
            agg[c]      = fmaxf(mx, mx2);
            agg[PP + c] = (sm + sm2) * (1.f / (float)KSEL);
        }
    }
    WSYNC();

    // ---- epilogue: out = tanh([x | max | mean] @ Wo + bo), fast tanh ----
    if (lane < FOUT) {
        const float* xr = x + (size_t)qj * FIN;
        float acc = bo[lane];
        #pragma unroll
        for (int f = 0; f < FIN; ++f)
            acc = fmaf(xr[f], Wo[f * FOUT + lane], acc);
        #pragma unroll
        for (int f = 0; f < 2 * PP; ++f)
            acc = fmaf(agg[f], Wo[(FIN + f) * FOUT + lane], acc);
        float e = __expf(2.f * acc);
        float r = __builtin_amdgcn_rcpf(e + 1.f);
        out[(size_t)qj * FOUT + lane] = fmaf(-2.f, r, 1.f);
    }
    WSYNC();
}

// ---------------- main: one wave per FOUR queries, fully scalarized --------------
__global__ __launch_bounds__(WPB * 64, 5) void gn_main(
    const float* __restrict__ x,
    const float* __restrict__ Wo, const float* __restrict__ bo,
    const float* __restrict__ coords4, const float* __restrict__ feats,
    float* __restrict__ out)
{
    __shared__ unsigned short sel_s[WPB * QW * CAP];     // candidate indices
    __shared__ float fstage_s[WPB * KSEL * PPAD];
    __shared__ float agg_s[WPB * 48];
    __shared__ unsigned cnt_s[WPB * QW];
    __shared__ unsigned cnt2_s[WPB];

    const float INF = __builtin_inff();
    const int wv    = threadIdx.x >> 6;
    const int lane  = threadIdx.x & 63;
    const int qbase = (blockIdx.x * WPB + wv) * QW;      // 4 queries, same batch
    const int b     = qbase >> 12;
    const int n0    = qbase & (NN - 1);
    unsigned short* selp = sel_s + wv * QW * CAP;
    float* fstage = fstage_s + wv * (KSEL * PPAD);
    float* agg    = agg_s + wv * 48;

    const float4* c4 = ((const float4*)coords4) + (size_t)b * NN;

    // per-query constants -- individual scalars only
    float4 cq0 = c4[n0 + 0], cq1 = c4[n0 + 1], cq2 = c4[n0 + 2], cq3 = c4[n0 + 3];
    float sq0 = fmaf(cq0.x, cq0.x, fmaf(cq0.y, cq0.y, fmaf(cq0.z, cq0.z, cq0.w * cq0.w)));
    float sq1 = fmaf(cq1.x, cq1.x, fmaf(cq1.y, cq1.y, fmaf(cq1.z, cq1.z, cq1.w * cq1.w)));
    float sq2 = fmaf(cq2.x, cq2.x, fmaf(cq2.y, cq2.y, fmaf(cq2.z, cq2.z, cq2.w * cq2.w)));
    float sq3 = fmaf(cq3.x, cq3.x, fmaf(cq3.y, cq3.y, fmaf(cq3.z, cq3.z, cq3.w * cq3.w)));

    if (lane < QW) cnt_s[wv * QW + lane] = 0;

    // ---- pass 1: shared |cm|^2, per-query running min (self included) ----
    float km0 = INF, km1 = INF, km2 = INF, km3 = INF;
    #pragma unroll 4
    for (int i = 0; i < 64; ++i) {
        float4 cm = c4[i * 64 + lane];
        float s2 = fmaf(cm.x, cm.x, fmaf(cm.y, cm.y, fmaf(cm.z, cm.z, cm.w * cm.w)));
        float dt0 = fmaf(cq0.x, cm.x, fmaf(cq0.y, cm.y, fmaf(cq0.z, cm.z, cq0.w * cm.w)));
        float dt1 = fmaf(cq1.x, cm.x, fmaf(cq1.y, cm.y, fmaf(cq1.z, cm.z, cq1.w * cm.w)));
        float dt2 = fmaf(cq2.x, cm.x, fmaf(cq2.y, cm.y, fmaf(cq2.z, cm.z, cq2.w * cm.w)));
        float dt3 = fmaf(cq3.x, cm.x, fmaf(cq3.y, cm.y, fmaf(cq3.z, cm.z, cq3.w * cm.w)));
        km0 = fminf(km0, fmaf(-2.f, dt0, s2 + sq0));
        km1 = fminf(km1, fmaf(-2.f, dt1, s2 + sq1));
        km2 = fminf(km2, fmaf(-2.f, dt2, s2 + sq2));
        km3 = fminf(km3, fmaf(-2.f, dt3, s2 + sq3));
    }
    unsigned kb0 = __float_as_uint(fmaxf(km0, 0.f));
    unsigned kb1 = __float_as_uint(fmaxf(km1, 0.f));
    unsigned kb2 = __float_as_uint(fmaxf(km2, 0.f));
    unsigned kb3 = __float_as_uint(fmaxf(km3, 0.f));

    // ---- bounds: exact 40th-smallest lane-min per query (scalars, interleaved) ----
    unsigned ub0 = 0, ub1 = 0, ub2 = 0, ub3 = 0;
    for (int bit = 30; bit >= 0; --bit) {
        unsigned msk = 1u << bit;
        unsigned t0 = ub0 | msk, t1 = ub1 | msk, t2 = ub2 | msk, t3 = ub3 | msk;
        if ((int)__popcll(__ballot(kb0 < t0)) < KSEL + 1) ub0 = t0;
        if ((int)__popcll(__ballot(kb1 < t1)) < KSEL + 1) ub1 = t1;
        if ((int)__popcll(__ballot(kb2 < t2)) < KSEL + 1) ub2 = t2;
        if ((int)__popcll(__ballot(kb3 < t3)) < KSEL + 1) ub3 = t3;
    }
    float UB0 = __uint_as_float(ub0), UB1 = __uint_as_float(ub1);
    float UB2 = __uint_as_float(ub2), UB3 = __uint_as_float(ub3);
    WSYNC();   // cnt init visible

    // ---- compact pass: per-query candidate index lists (scalars only) ----
    #pragma unroll 4
    for (int i = 0; i < 64; ++i) {
        int m = i * 64 + lane;
        float4 cm = c4[m];
        float s2 = fmaf(cm.x, cm.x, fmaf(cm.y, cm.y, fmaf(cm.z, cm.z, cm.w * cm.w)));
        float dt0 = fmaf(cq0.x, cm.x, fmaf(cq0.y, cm.y, fmaf(cq0.z, cm.z, cq0.w * cm.w)));
        float dt1 = fmaf(cq1.x, cm.x, fmaf(cq1.y, cm.y, fmaf(cq1.z, cm.z, cq1.w * cm.w)));
        float dt2 = fmaf(cq2.x, cm.x, fmaf(cq2.y, cm.y, fmaf(cq2.z, cm.z, cq2.w * cm.w)));
        float dt3 = fmaf(cq3.x, cm.x, fmaf(cq3.y, cm.y, fmaf(cq3.z, cm.z, cq3.w * cm.w)));
        float d0 = fmaf(-2.f, dt0, s2 + sq0);
        float d1 = fmaf(-2.f, dt1, s2 + sq1);
        float d2 = fmaf(-2.f, dt2, s2 + sq2);
        float d3 = fmaf(-2.f, dt3, s2 + sq3);
        if ((d0 <= UB0) && (m != n0 + 0)) {
            unsigned s = atomicAdd(&cnt_s[wv * QW + 0], 1u);
            if (s < CAP) selp[0 * CAP + s] = (unsigned short)m;
        }
        if ((d1 <= UB1) && (m != n0 + 1)) {
            unsigned s = atomicAdd(&cnt_s[wv * QW + 1], 1u);
            if (s < CAP) selp[1 * CAP + s] = (unsigned short)m;
        }
        if ((d2 <= UB2) && (m != n0 + 2)) {
            unsigned s = atomicAdd(&cnt_s[wv * QW + 2], 1u);
            if (s < CAP) selp[2 * CAP + s] = (unsigned short)m;
        }
        if ((d3 <= UB3) && (m != n0 + 3)) {
            unsigned s = atomicAdd(&cnt_s[wv * QW + 3], 1u);
            if (s < CAP) selp[3 * CAP + s] = (unsigned short)m;
        }
    }
    WSYNC();

    // ---- four explicit tail calls (no runtime-indexed private state) ----
    tail_query(lane, b, n0 + 0, qbase + 0, (int)cnt_s[wv * QW + 0], selp + 0 * CAP,
               c4, feats, x, Wo, bo, fstage, agg, &cnt2_s[wv], out);
    tail_query(lane, b, n0 + 1, qbase + 1, (int)cnt_s[wv * QW + 1], selp + 1 * CAP,
               c4, feats, x, Wo, bo, fstage, agg, &cnt2_s[wv], out);
    tail_query(lane, b, n0 + 2, qbase + 2, (int)cnt_s[wv * QW + 2], selp + 2 * CAP,
               c4, feats, x, Wo, bo, fstage, agg, &cnt2_s[wv], out);
    tail_query(lane, b, n0 + 3, qbase + 3, (int)cnt_s[wv * QW + 3], selp + 3 * CAP,
               c4, feats, x, Wo, bo, fstage, agg, &cnt2_s[wv], out);
}

extern "C" void kernel_launch(void* const* d_in, const int* in_sizes, int n_in,
                              void* d_out, int out_size, void* d_ws, size_t ws_size,
                              hipStream_t stream) {
    const float* x  = (const float*)d_in[0];
    const float* Wf = (const float*)d_in[1];
    const float* bf = (const float*)d_in[2];
    const float* Ws = (const float*)d_in[3];
    const float* bs = (const float*)d_in[4];
    const float* Wo = (const float*)d_in[5];
    const float* bo = (const float*)d_in[6];
    float* outp = (float*)d_out;

    float* ws      = (float*)d_ws;
    float* coords4 = ws;                      // 32768*4  = 131072 floats
    float* feats   = ws + 131072;             // 32768*24 = 786432 floats

    gn_pre<<<32768 / 256, 256, 0, stream>>>(x, Wf, bf, Ws, bs, coords4, feats);
    gn_main<<<32768 / (WPB * QW), WPB * 64, 0, stream>>>(x, Wo, bo, coords4, feats, outp);
}

// Round 12
// 201.084 us; speedup vs baseline: 2.4452x; 1.1531x over previous
//
#include <hip/hip_runtime.h>
#include <cmath>

#define NN    4096
#define FIN   32
#define KSEL  39      // neighbors kept (top-40 minus self)
#define PP    22
#define PPAD  24
#define FOUT  48
#define WPB   2       // waves per block
#define QW    4       // queries per wave
#define CAP   128     // candidate cap per query (fallback if exceeded)

#define WSYNC() asm volatile("s_waitcnt lgkmcnt(0)" ::: "memory")

// ---------------- precompute: one thread per point -------------------------------
__global__ __launch_bounds__(256) void gn_pre(
    const float* __restrict__ x,
    const float* __restrict__ Wf, const float* __restrict__ bf,
    const float* __restrict__ Ws, const float* __restrict__ bs,
    float* __restrict__ coords4, float* __restrict__ feats)
{
    int p = blockIdx.x * 256 + threadIdx.x;

    const float4* xr4 = (const float4*)(x + (size_t)p * FIN);
    float xv[FIN];
    #pragma unroll
    for (int i = 0; i < 8; ++i) {
        float4 t = xr4[i];
        xv[4*i] = t.x; xv[4*i+1] = t.y; xv[4*i+2] = t.z; xv[4*i+3] = t.w;
    }

    float fa[PP];
    #pragma unroll
    for (int c = 0; c < PP; ++c) fa[c] = bf[c];
    #pragma unroll
    for (int i = 0; i < FIN; ++i) {
        float xi = xv[i];
        #pragma unroll
        for (int c = 0; c < PP; ++c) fa[c] = fmaf(xi, Wf[i * PP + c], fa[c]);
    }

    float ca[4];
    #pragma unroll
    for (int c = 0; c < 4; ++c) ca[c] = bs[c];
    #pragma unroll
    for (int i = 0; i < FIN; ++i) {
        float xi = xv[i];
        #pragma unroll
        for (int c = 0; c < 4; ++c) ca[c] = fmaf(xi, Ws[i * 4 + c], ca[c]);
    }

    float4* fw = (float4*)(feats + (size_t)p * PPAD);
    fw[0] = make_float4(fa[0],  fa[1],  fa[2],  fa[3]);
    fw[1] = make_float4(fa[4],  fa[5],  fa[6],  fa[7]);
    fw[2] = make_float4(fa[8],  fa[9],  fa[10], fa[11]);
    fw[3] = make_float4(fa[12], fa[13], fa[14], fa[15]);
    fw[4] = make_float4(fa[16], fa[17], fa[18], fa[19]);
    fw[5] = make_float4(fa[20], fa[21], 0.f, 0.f);

    ((float4*)coords4)[p] = make_float4(ca[0], ca[1], ca[2], ca[3]);
}

// ---- fallback-only helpers (degenerate C > CAP path) ----------------------------
__device__ __forceinline__ void sort64_pair(float& v, int& m, int lane) {
    #pragma unroll
    for (int k = 2; k <= 64; k <<= 1) {
        #pragma unroll
        for (int j = k >> 1; j >= 1; j >>= 1) {
            float ov = __shfl_xor(v, j);
            int   om = __shfl_xor(m, j);
            bool keepMin = (((lane & j) == 0) == ((lane & k) == 0));
            bool less = (ov < v) || (ov == v && om < m);
            bool take = (less == keepMin);
            v = take ? ov : v;
            m = take ? om : m;
        }
    }
}
__device__ __forceinline__ void merge64(float& Lv, int& Lm, float cv, int cm, int lane) {
    float rv = __shfl_xor(cv, 63);
    int   rm = __shfl_xor(cm, 63);
    bool less = (rv < Lv) || (rv == Lv && rm < Lm);
    if (less) { Lv = rv; Lm = rm; }
    #pragma unroll
    for (int j = 32; j >= 1; j >>= 1) {
        float ov = __shfl_xor(Lv, j);
        int   om = __shfl_xor(Lm, j);
        bool lower = ((lane & j) == 0);
        bool l2 = (ov < Lv) || (ov == Lv && om < Lm);
        bool take = (l2 == lower);
        Lv = take ? ov : Lv;
        Lm = take ? om : Lm;
    }
}

// ---------------- per-query tail: selection + stage + aggregate + epilogue -------
// ALL state is scalar. Called 4 times explicitly (no runtime-j loop, no arrays --
// runtime-indexed private arrays demote to scratch: R9/R10's 30x HBM regression).
__device__ __forceinline__ void tail_query(
    int lane, int b, int nj, int qj, int C,
    const unsigned short* __restrict__ selq,
    const float4* __restrict__ c4, const float* __restrict__ feats,
    const float* __restrict__ x, const float* __restrict__ Wo,
    const float* __restrict__ bo,
    float* __restrict__ fstage, float* __restrict__ agg,
    unsigned* __restrict__ cnt2, float* __restrict__ out)
{
    const float INF = __builtin_inff();
    const float NEGINF = -INF;
    float4 cqj = c4[nj];
    float sqnj = fmaf(cqj.x, cqj.x, fmaf(cqj.y, cqj.y, fmaf(cqj.z, cqj.z, cqj.w * cqj.w)));

    if (lane == 0) *cnt2 = 0;
    WSYNC();

    if (C <= CAP) {
        unsigned kd0 = 0xFFFFFFFFu, ki0 = 0xFFFFFFFFu; float dv0 = 0.f;
        if (lane < C) {
            unsigned idx = (unsigned)selq[lane];
            float4 cm = c4[idx];
            float s2 = fmaf(cm.x, cm.x, fmaf(cm.y, cm.y, fmaf(cm.z, cm.z, cm.w * cm.w)));
            float dt = fmaf(cqj.x, cm.x, fmaf(cqj.y, cm.y, fmaf(cqj.z, cm.z, cqj.w * cm.w)));
            float d  = fmaxf(fmaf(-2.f, dt, s2 + sqnj), 0.f);
            dv0 = d; kd0 = __float_as_uint(d); ki0 = idx;
        }
        unsigned kd1 = 0xFFFFFFFFu, ki1 = 0xFFFFFFFFu; float dv1 = 0.f;
        if (64 + lane < C) {
            unsigned idx = (unsigned)selq[64 + lane];
            float4 cm = c4[idx];
            float s2 = fmaf(cm.x, cm.x, fmaf(cm.y, cm.y, fmaf(cm.z, cm.z, cm.w * cm.w)));
            float dt = fmaf(cqj.x, cm.x, fmaf(cqj.y, cm.y, fmaf(cqj.z, cm.z, cqj.w * cm.w)));
            float d  = fmaxf(fmaf(-2.f, dt, s2 + sqnj), 0.f);
            dv1 = d; kd1 = __float_as_uint(d); ki1 = idx;
        }
        // D = exact 39th-smallest clamped d2 bits (must stay exact)
        unsigned D = 0;
        for (int bit = 30; bit >= 0; --bit) {
            unsigned t = D | (1u << bit);
            int c = (int)__popcll(__ballot(kd0 < t))
                  + (int)__popcll(__ballot(kd1 < t));
            if (c < KSEL) D = t;
        }
        int cless  = (int)__popcll(__ballot(kd0 < D))
                   + (int)__popcll(__ballot(kd1 < D));
        int tiecnt = (int)__popcll(__ballot(kd0 == D))
                   + (int)__popcll(__ballot(kd1 == D));
        int tneed = KSEL - cless;
        unsigned TI = 0xFFFFFFFFu;
        if (tiecnt > tneed) {            // rare: resolve ties by lowest index
            unsigned pi = 0;
            for (int bit = 11; bit >= 0; --bit) {
                unsigned t = pi | (1u << bit);
                int c = (int)__popcll(__ballot((kd0 == D) && (ki0 < t)))
                      + (int)__popcll(__ballot((kd1 == D) && (ki1 < t)));
                if (c < tneed) pi = t;
            }
            TI = pi;
        }
        // stage the exactly-39 selected neighbors
        bool take0 = (kd0 < D) || ((kd0 == D) && (ki0 <= TI));
        if (take0) {
            unsigned slot = atomicAdd(cnt2, 1u);
            float wgt = __expf(-10.f * dv0);
            const float4* fr = (const float4*)(feats + ((size_t)b * NN + ki0) * PPAD);
            float4 f0 = fr[0], f1 = fr[1], f2 = fr[2], f3 = fr[3], f4 = fr[4], f5 = fr[5];
            float4* row = (float4*)(fstage + slot * PPAD);
            row[0] = make_float4(f0.x * wgt, f0.y * wgt, f0.z * wgt, f0.w * wgt);
            row[1] = make_float4(f1.x * wgt, f1.y * wgt, f1.z * wgt, f1.w * wgt);
            row[2] = make_float4(f2.x * wgt, f2.y * wgt, f2.z * wgt, f2.w * wgt);
            row[3] = make_float4(f3.x * wgt, f3.y * wgt, f3.z * wgt, f3.w * wgt);
            row[4] = make_float4(f4.x * wgt, f4.y * wgt, f4.z * wgt, f4.w * wgt);
            row[5] = make_float4(f5.x * wgt, f5.y * wgt, f5.z * wgt, f5.w * wgt);
        }
        bool take1 = (kd1 < D) || ((kd1 == D) && (ki1 <= TI));
        if (take1) {
            unsigned slot = atomicAdd(cnt2, 1u);
            float wgt = __expf(-10.f * dv1);
            const float4* fr = (const float4*)(feats + ((size_t)b * NN + ki1) * PPAD);
            float4 f0 = fr[0], f1 = fr[1], f2 = fr[2], f3 = fr[3], f4 = fr[4], f5 = fr[5];
            float4* row = (float4*)(fstage + slot * PPAD);
            row[0] = make_float4(f0.x * wgt, f0.y * wgt, f0.z * wgt, f0.w * wgt);
            row[1] = make_float4(f1.x * wgt, f1.y * wgt, f1.z * wgt, f1.w * wgt);
            row[2] = make_float4(f2.x * wgt, f2.y * wgt, f2.z * wgt, f2.w * wgt);
            row[3] = make_float4(f3.x * wgt, f3.y * wgt, f3.z * wgt, f3.w * wgt);
            row[4] = make_float4(f4.x * wgt, f4.y * wgt, f4.z * wgt, f4.w * wgt);
            row[5] = make_float4(f5.x * wgt, f5.y * wgt, f5.z * wgt, f5.w * wgt);
        }
    } else {
        // degenerate fallback: exact streaming top-64 over all 4096
        float Lv = INF; int Lm = 0x7FFFFFFF;
        for (int c = 0; c < 64; ++c) {
            int m = c * 64 + lane;
            float4 cm = c4[m];
            float s2 = fmaf(cm.x, cm.x, fmaf(cm.y, cm.y, fmaf(cm.z, cm.z, cm.w * cm.w)));
            float dt = fmaf(cqj.x, cm.x, fmaf(cqj.y, cm.y, fmaf(cqj.z, cm.z, cqj.w * cm.w)));
            float v  = fmaxf(fmaf(-2.f, dt, s2 + sqnj), 0.f);
            if (m == nj) v = INF;
            sort64_pair(v, m, lane);
            if (c == 0) { Lv = v; Lm = m; }
            else        merge64(Lv, Lm, v, m, lane);
        }
        if (lane < KSEL) {
            float wgt = __expf(-10.f * Lv);
            const float4* fr = (const float4*)(feats + ((size_t)b * NN + Lm) * PPAD);
            float4 f0 = fr[0], f1 = fr[1], f2 = fr[2], f3 = fr[3], f4 = fr[4], f5 = fr[5];
            float4* row = (float4*)(fstage + lane * PPAD);
            row[0] = make_float4(f0.x * wgt, f0.y * wgt, f0.z * wgt, f0.w * wgt);
            row[1] = make_float4(f1.x * wgt, f1.y * wgt, f1.z * wgt, f1.w * wgt);
            row[2] = make_float4(f2.x * wgt, f2.y * wgt, f2.z * wgt, f2.w * wgt);
            row[3] = make_float4(f3.x * wgt, f3.y * wgt, f3.z * wgt, f3.w * wgt);
            row[4] = make_float4(f4.x * wgt, f4.y * wgt, f4.z * wgt, f4.w * wgt);
            row[5] = make_float4(f5.x * wgt, f5.y * wgt, f5.z * wgt, f5.w * wgt);
        }
    }
    WSYNC();

    // ---- max / mean over 39 neighbors: 44 lanes, split-k ----
    if (lane < 2 * PP) {
        int g  = (lane >= PP) ? 1 : 0;
        int c  = lane - g * PP;
        int k0 = g ? 20 : 0;
        int k1 = g ? KSEL : 20;
        float mx = NEGINF, sm = 0.f;
        for (int k = k0; k < k1; ++k) {
            float v = fstage[k * PPAD + c];
            mx = fmaxf(mx, v);
            sm += v;
        }
        float mx2 = __shfl(mx, lane + PP);
        float sm2 = __shfl(sm, lane + PP);
        if (lane < PP) {
            agg[c]      = fmaxf(mx, mx2);
            agg[PP + c] = (sm + sm2) * (1.f / (float)KSEL);
        }
    }
    WSYNC();

    // ---- epilogue: out = tanh([x | max | mean] @ Wo + bo), fast tanh ----
    if (lane < FOUT) {
        const float* xr = x + (size_t)qj * FIN;
        float acc = bo[lane];
        #pragma unroll
        for (int f = 0; f < FIN; ++f)
            acc = fmaf(xr[f], Wo[f * FOUT + lane], acc);
        #pragma unroll
        for (int f = 0; f < 2 * PP; ++f)
            acc = fmaf(agg[f], Wo[(FIN + f) * FOUT + lane], acc);
        float e = __expf(2.f * acc);
        float r = __builtin_amdgcn_rcpf(e + 1.f);
        out[(size_t)qj * FOUT + lane] = fmaf(-2.f, r, 1.f);
    }
    WSYNC();
}

// ---------------- main: one wave per FOUR queries, fully scalarized --------------
__global__ __launch_bounds__(WPB * 64, 8) void gn_main(
    const float* __restrict__ x,
    const float* __restrict__ Wo, const float* __restrict__ bo,
    const float* __restrict__ coords4, const float* __restrict__ feats,
    float* __restrict__ out)
{
    __shared__ unsigned short sel_s[WPB * QW * CAP];     // candidate indices
    __shared__ float fstage_s[WPB * KSEL * PPAD];
    __shared__ float agg_s[WPB * 48];
    __shared__ unsigned cnt_s[WPB * QW];
    __shared__ unsigned cnt2_s[WPB];

    const float INF = __builtin_inff();
    const int wv    = threadIdx.x >> 6;
    const int lane  = threadIdx.x & 63;
    const int qbase = (blockIdx.x * WPB + wv) * QW;      // 4 queries, same batch
    const int b     = qbase >> 12;
    const int n0    = qbase & (NN - 1);
    unsigned short* selp = sel_s + wv * QW * CAP;
    float* fstage = fstage_s + wv * (KSEL * PPAD);
    float* agg    = agg_s + wv * 48;

    const float4* c4 = ((const float4*)coords4) + (size_t)b * NN;

    // per-query constants -- individual scalars only
    float4 cq0 = c4[n0 + 0], cq1 = c4[n0 + 1], cq2 = c4[n0 + 2], cq3 = c4[n0 + 3];
    float sq0 = fmaf(cq0.x, cq0.x, fmaf(cq0.y, cq0.y, fmaf(cq0.z, cq0.z, cq0.w * cq0.w)));
    float sq1 = fmaf(cq1.x, cq1.x, fmaf(cq1.y, cq1.y, fmaf(cq1.z, cq1.z, cq1.w * cq1.w)));
    float sq2 = fmaf(cq2.x, cq2.x, fmaf(cq2.y, cq2.y, fmaf(cq2.z, cq2.z, cq2.w * cq2.w)));
    float sq3 = fmaf(cq3.x, cq3.x, fmaf(cq3.y, cq3.y, fmaf(cq3.z, cq3.z, cq3.w * cq3.w)));

    if (lane < QW) cnt_s[wv * QW + lane] = 0;

    // ---- pass 1: shared |cm|^2, per-query running min (self included) ----
    float km0 = INF, km1 = INF, km2 = INF, km3 = INF;
    #pragma unroll 4
    for (int i = 0; i < 64; ++i) {
        float4 cm = c4[i * 64 + lane];
        float s2 = fmaf(cm.x, cm.x, fmaf(cm.y, cm.y, fmaf(cm.z, cm.z, cm.w * cm.w)));
        float dt0 = fmaf(cq0.x, cm.x, fmaf(cq0.y, cm.y, fmaf(cq0.z, cm.z, cq0.w * cm.w)));
        float dt1 = fmaf(cq1.x, cm.x, fmaf(cq1.y, cm.y, fmaf(cq1.z, cm.z, cq1.w * cm.w)));
        float dt2 = fmaf(cq2.x, cm.x, fmaf(cq2.y, cm.y, fmaf(cq2.z, cm.z, cq2.w * cm.w)));
        float dt3 = fmaf(cq3.x, cm.x, fmaf(cq3.y, cm.y, fmaf(cq3.z, cm.z, cq3.w * cm.w)));
        km0 = fminf(km0, fmaf(-2.f, dt0, s2 + sq0));
        km1 = fminf(km1, fmaf(-2.f, dt1, s2 + sq1));
        km2 = fminf(km2, fmaf(-2.f, dt2, s2 + sq2));
        km3 = fminf(km3, fmaf(-2.f, dt3, s2 + sq3));
    }
    unsigned kb0 = __float_as_uint(fmaxf(km0, 0.f));
    unsigned kb1 = __float_as_uint(fmaxf(km1, 0.f));
    unsigned kb2 = __float_as_uint(fmaxf(km2, 0.f));
    unsigned kb3 = __float_as_uint(fmaxf(km3, 0.f));

    // ---- bounds: 40th-smallest lane-min per query, TRUNCATED radix (bits 30..15)
    //      then widen low bits: UB' = p + 2^15 - 1 >= exact 40th value.
    //      Still an exact superset; only the candidate count grows (~0 extra).
    unsigned ub0 = 0, ub1 = 0, ub2 = 0, ub3 = 0;
    for (int bit = 30; bit >= 15; --bit) {
        unsigned msk = 1u << bit;
        unsigned t0 = ub0 | msk, t1 = ub1 | msk, t2 = ub2 | msk, t3 = ub3 | msk;
        if ((int)__popcll(__ballot(kb0 < t0)) < KSEL + 1) ub0 = t0;
        if ((int)__popcll(__ballot(kb1 < t1)) < KSEL + 1) ub1 = t1;
        if ((int)__popcll(__ballot(kb2 < t2)) < KSEL + 1) ub2 = t2;
        if ((int)__popcll(__ballot(kb3 < t3)) < KSEL + 1) ub3 = t3;
    }
    float UB0 = __uint_as_float(ub0 | 0x7FFFu);
    float UB1 = __uint_as_float(ub1 | 0x7FFFu);
    float UB2 = __uint_as_float(ub2 | 0x7FFFu);
    float UB3 = __uint_as_float(ub3 | 0x7FFFu);
    WSYNC();   // cnt init visible

    // ---- compact pass: per-query candidate index lists (scalars only) ----
    #pragma unroll 4
    for (int i = 0; i < 64; ++i) {
        int m = i * 64 + lane;
        float4 cm = c4[m];
        float s2 = fmaf(cm.x, cm.x, fmaf(cm.y, cm.y, fmaf(cm.z, cm.z, cm.w * cm.w)));
        float dt0 = fmaf(cq0.x, cm.x, fmaf(cq0.y, cm.y, fmaf(cq0.z, cm.z, cq0.w * cm.w)));
        float dt1 = fmaf(cq1.x, cm.x, fmaf(cq1.y, cm.y, fmaf(cq1.z, cm.z, cq1.w * cm.w)));
        float dt2 = fmaf(cq2.x, cm.x, fmaf(cq2.y, cm.y, fmaf(cq2.z, cm.z, cq2.w * cm.w)));
        float dt3 = fmaf(cq3.x, cm.x, fmaf(cq3.y, cm.y, fmaf(cq3.z, cm.z, cq3.w * cm.w)));
        float d0 = fmaf(-2.f, dt0, s2 + sq0);
        float d1 = fmaf(-2.f, dt1, s2 + sq1);
        float d2 = fmaf(-2.f, dt2, s2 + sq2);
        float d3 = fmaf(-2.f, dt3, s2 + sq3);
        if ((d0 <= UB0) && (m != n0 + 0)) {
            unsigned s = atomicAdd(&cnt_s[wv * QW + 0], 1u);
            if (s < CAP) selp[0 * CAP + s] = (unsigned short)m;
        }
        if ((d1 <= UB1) && (m != n0 + 1)) {
            unsigned s = atomicAdd(&cnt_s[wv * QW + 1], 1u);
            if (s < CAP) selp[1 * CAP + s] = (unsigned short)m;
        }
        if ((d2 <= UB2) && (m != n0 + 2)) {
            unsigned s = atomicAdd(&cnt_s[wv * QW + 2], 1u);
            if (s < CAP) selp[2 * CAP + s] = (unsigned short)m;
        }
        if ((d3 <= UB3) && (m != n0 + 3)) {
            unsigned s = atomicAdd(&cnt_s[wv * QW + 3], 1u);
            if (s < CAP) selp[3 * CAP + s] = (unsigned short)m;
        }
    }
    WSYNC();

    // ---- four explicit tail calls (no runtime-indexed private state) ----
    tail_query(lane, b, n0 + 0, qbase + 0, (int)cnt_s[wv * QW + 0], selp + 0 * CAP,
               c4, feats, x, Wo, bo, fstage, agg, &cnt2_s[wv], out);
    tail_query(lane, b, n0 + 1, qbase + 1, (int)cnt_s[wv * QW + 1], selp + 1 * CAP,
               c4, feats, x, Wo, bo, fstage, agg, &cnt2_s[wv], out);
    tail_query(lane, b, n0 + 2, qbase + 2, (int)cnt_s[wv * QW + 2], selp + 2 * CAP,
               c4, feats, x, Wo, bo, fstage, agg, &cnt2_s[wv], out);
    tail_query(lane, b, n0 + 3, qbase + 3, (int)cnt_s[wv * QW + 3], selp + 3 * CAP,
               c4, feats, x, Wo, bo, fstage, agg, &cnt2_s[wv], out);
}

extern "C" void kernel_launch(void* const* d_in, const int* in_sizes, int n_in,
                              void* d_out, int out_size, void* d_ws, size_t ws_size,
                              hipStream_t stream) {
    const float* x  = (const float*)d_in[0];
    const float* Wf = (const float*)d_in[1];
    const float* bf = (const float*)d_in[2];
    const float* Ws = (const float*)d_in[3];
    const float* bs = (const float*)d_in[4];
    const float* Wo = (const float*)d_in[5];
    const float* bo = (const float*)d_in[6];
    float* outp = (float*)d_out;

    float* ws      = (float*)d_ws;
    float* coords4 = ws;                      // 32768*4  = 131072 floats
    float* feats   = ws + 131072;             // 32768*24 = 786432 floats

    gn_pre<<<32768 / 256, 256, 0, stream>>>(x, Wf, bf, Ws, bs, coords4, feats);
    gn_main<<<32768 / (WPB * QW), WPB * 64, 0, stream>>>(x, Wo, bo, coords4, feats, outp);
}